// Round 1
// baseline (567.566 us; speedup 1.0000x reference)
//
#include <hip/hip_runtime.h>
#include <hip/hip_bf16.h>
#include <math.h>

// Problem constants
#define B_    8
#define T_    2048
#define NTOK  (B_ * T_)   // 16384 tokens
#define D_    512
#define E_    8
#define CAP   NTOK        // per-expert bucket capacity (worst case)

typedef __attribute__((ext_vector_type(4))) float f32x4;
typedef __attribute__((ext_vector_type(8))) short short8;  // 8 bf16 = 4 VGPRs (MFMA a/b frag)

// ---------------------------------------------------------------------------
// async global->LDS, 16B per lane. LDS dest = wave-uniform base + lane*16.
// Global address may be per-lane scattered (gather is legal).
// ---------------------------------------------------------------------------
__device__ __forceinline__ void async_load16(const void* g, void* l) {
    __builtin_amdgcn_global_load_lds(
        (const __attribute__((address_space(1))) unsigned int*)g,
        (__attribute__((address_space(3))) unsigned int*)l,
        16, 0, 0);
}

// ---------------------------------------------------------------------------
// Kernel 1: transpose + convert Wk[e][d][h] (fp32) -> Wkt[e][h][d] (bf16).
// Gives the expert GEMM a B^T ([n][k]) row-major layout so B fragments are
// contiguous ds_read_b128, same as the verified gemm_bt structure.
// ---------------------------------------------------------------------------
__global__ __launch_bounds__(256) void transpose_wk(
    const float* __restrict__ Wk, __hip_bfloat16* __restrict__ Wkt)
{
    __shared__ float tile[32][33];  // +1 pad: no bank conflicts
    const int e  = blockIdx.z;
    const int d0 = blockIdx.x * 32;  // d_in
    const int h0 = blockIdx.y * 32;  // d_out
    const int tx = threadIdx.x, ty = threadIdx.y;

    const float* src = Wk + ((size_t)e * D_ + d0) * D_ + h0;
    #pragma unroll
    for (int r = ty; r < 32; r += 8)
        tile[r][tx] = src[(size_t)r * D_ + tx];
    __syncthreads();
    __hip_bfloat16* dst = Wkt + ((size_t)e * D_ + h0) * D_ + d0;
    #pragma unroll
    for (int r = ty; r < 32; r += 8)
        dst[(size_t)r * D_ + tx] = __float2bfloat16(tile[tx][r]);
}

// ---------------------------------------------------------------------------
// Kernel 2: router. One wave (64 lanes) per token.
//  - fp32 dot products x.Wr, x.Wn (exact-precision router: bf16 here could
//    flip near-tied top-2 picks and blow absmax by O(0.3))
//  - exact softplus, top-2 w/ lax.top_k tie semantics, 2-way softmax gate
//  - fused x -> bf16 conversion (row is already in registers)
//  - atomic scatter into per-expert buckets {token, gate}
// ---------------------------------------------------------------------------
__global__ __launch_bounds__(256) void router_kernel(
    const float* __restrict__ x,    // [NTOK][D]
    const float* __restrict__ eps,  // [NTOK][E]
    const float* __restrict__ Wr,   // [D][E]
    const float* __restrict__ br,   // [E]
    const float* __restrict__ Wn,   // [D][E]
    const float* __restrict__ bn,   // [E]
    __hip_bfloat16* __restrict__ xb,  // out: [NTOK][D] bf16
    int* __restrict__ counts,         // [E] (pre-zeroed)
    uint2* __restrict__ entries)      // [E][CAP] {token, gate_bits}
{
    const int lane = threadIdx.x & 63;
    const int tok  = blockIdx.x * 4 + (threadIdx.x >> 6);  // grid covers NTOK waves exactly

    const float* xrow = x + (size_t)tok * D_;
    float xv[8];
    *(f32x4*)(xv)     = *(const f32x4*)(xrow + lane * 8);
    *(f32x4*)(xv + 4) = *(const f32x4*)(xrow + lane * 8 + 4);

    // fused bf16 conversion of x (coalesced 16B/lane store)
    union { __hip_bfloat16 h[8]; uint4 u; } cv;
    #pragma unroll
    for (int j = 0; j < 8; ++j) cv.h[j] = __float2bfloat16(xv[j]);
    *(uint4*)(xb + (size_t)tok * D_ + lane * 8) = cv.u;

    float aR[8] = {0, 0, 0, 0, 0, 0, 0, 0};
    float aN[8] = {0, 0, 0, 0, 0, 0, 0, 0};
    #pragma unroll
    for (int j = 0; j < 8; ++j) {
        const int d = lane * 8 + j;
        union { f32x4 v[2]; float f[8]; } wr, wn;
        wr.v[0] = *(const f32x4*)(Wr + d * E_);
        wr.v[1] = *(const f32x4*)(Wr + d * E_ + 4);
        wn.v[0] = *(const f32x4*)(Wn + d * E_);
        wn.v[1] = *(const f32x4*)(Wn + d * E_ + 4);
        const float xd = xv[j];
        #pragma unroll
        for (int e2 = 0; e2 < 8; ++e2) {
            aR[e2] = fmaf(xd, wr.f[e2], aR[e2]);
            aN[e2] = fmaf(xd, wn.f[e2], aN[e2]);
        }
    }
    // butterfly reduce each of 16 accumulators across the 64-lane wave
    #pragma unroll
    for (int e2 = 0; e2 < 8; ++e2) {
        #pragma unroll
        for (int off = 32; off > 0; off >>= 1) {
            aR[e2] += __shfl_xor(aR[e2], off);
            aN[e2] += __shfl_xor(aN[e2], off);
        }
    }

    if (lane == 0) {
        float nv[8];
        #pragma unroll
        for (int e2 = 0; e2 < 8; ++e2) {
            const float nl = aN[e2] + bn[e2];
            // jax.nn.softplus = logaddexp(x, 0) = max(x,0) + log1p(exp(-|x|))
            const float sp = fmaxf(nl, 0.f) + log1pf(expf(-fabsf(nl)));
            nv[e2] = aR[e2] + br[e2] + eps[(size_t)tok * E_ + e2] * sp;
        }
        // top-2, lax.top_k tie semantics (lowest index wins ties)
        int i1 = 0; float v1 = nv[0];
        #pragma unroll
        for (int e2 = 1; e2 < 8; ++e2)
            if (nv[e2] > v1) { v1 = nv[e2]; i1 = e2; }
        int i2 = -1; float v2 = -3.4e38f;
        #pragma unroll
        for (int e2 = 0; e2 < 8; ++e2)
            if (e2 != i1 && nv[e2] > v2) { v2 = nv[e2]; i2 = e2; }
        // softmax over the two surviving logits (others are -inf)
        const float t  = expf(v2 - v1);
        const float g1 = 1.f / (1.f + t);
        const float g2 = t / (1.f + t);
        const int p1 = atomicAdd(counts + i1, 1);
        entries[(size_t)i1 * CAP + p1] = make_uint2((unsigned)tok, __float_as_uint(g1));
        const int p2 = atomicAdd(counts + i2, 1);
        entries[(size_t)i2 * CAP + p2] = make_uint2((unsigned)tok, __float_as_uint(g2));
    }
}

// ---------------------------------------------------------------------------
// Kernel 3: grouped expert GEMM. For expert e: C[rows of bucket e] =
// gather(xb) @ Wk[e] ; epilogue out[tok] += g * (acc + bk[e]) via atomicAdd.
// 128x128 tile, BK=32, 4 waves each computing 64x64 as 4x4 mfma 16x16x32.
// m97-style: global_load_lds(16B) staging, 2-barrier K-loop.
// ---------------------------------------------------------------------------
__global__ __launch_bounds__(256) void moe_gemm(
    const __hip_bfloat16* __restrict__ xb,   // [NTOK][D] bf16
    const __hip_bfloat16* __restrict__ wkt,  // [E][D(out)][D(in)] bf16 (B^T)
    const float* __restrict__ bk,            // [E][D]
    const int* __restrict__ counts,          // [E]
    const uint2* __restrict__ entries,       // [E][CAP]
    float* __restrict__ out)                 // [NTOK][D] fp32 (pre-zeroed)
{
    constexpr int BM = 128, BN = 128, BK = 32;
    __shared__ __hip_bfloat16 As[BM * BK];   // [m][k] packed (no pad: global_load_lds)
    __shared__ __hip_bfloat16 Bs[BN * BK];   // [n][k] packed
    __shared__ uint2 ent[BM];

    const int e  = blockIdx.z;
    const int mt = blockIdx.y;
    const int nt = blockIdx.x;
    const int cnt = counts[e];
    if (mt * BM >= cnt) return;  // uniform early-exit for unused tiles

    const int tid = threadIdx.x;
    const int wave = tid >> 6, lane = tid & 63;

    if (tid < BM) {
        const int idx = mt * BM + tid;
        ent[tid] = (idx < cnt) ? entries[(size_t)e * CAP + idx] : make_uint2(0u, 0u);
    }
    __syncthreads();

    const int quad = lane >> 4, lr = lane & 15;
    const int wm = wave >> 1, wn = wave & 1;
    const int sub = lane >> 2, part = lane & 3;  // staging: 16 rows x 4 chunks per instr

    f32x4 acc[4][4];
    #pragma unroll
    for (int i = 0; i < 4; ++i)
        #pragma unroll
        for (int j = 0; j < 4; ++j) acc[i][j] = (f32x4){0.f, 0.f, 0.f, 0.f};

    // this wave stages A rows [wave*32, wave*32+32) and same B rows
    const size_t tok0 = ent[wave * 32 + sub].x;
    const size_t tok1 = ent[wave * 32 + 16 + sub].x;
    const size_t brow0 = (size_t)e * D_ + nt * BN + wave * 32 + sub;

    for (int k0 = 0; k0 < D_; k0 += BK) {
        async_load16(xb + tok0 * D_ + k0 + part * 8, As + (wave * 32) * BK);
        async_load16(xb + tok1 * D_ + k0 + part * 8, As + (wave * 32 + 16) * BK);
        async_load16(wkt + brow0 * D_ + k0 + part * 8, Bs + (wave * 32) * BK);
        async_load16(wkt + (brow0 + 16) * D_ + k0 + part * 8, Bs + (wave * 32 + 16) * BK);
        __syncthreads();  // drains vmcnt -> staged data visible

        short8 a[4], b[4];
        #pragma unroll
        for (int i = 0; i < 4; ++i)
            a[i] = *(const short8*)(As + (wm * 64 + i * 16 + lr) * BK + quad * 8);
        #pragma unroll
        for (int j = 0; j < 4; ++j)
            b[j] = *(const short8*)(Bs + (wn * 64 + j * 16 + lr) * BK + quad * 8);
        #pragma unroll
        for (int i = 0; i < 4; ++i)
            #pragma unroll
            for (int j = 0; j < 4; ++j)
                acc[i][j] = __builtin_amdgcn_mfma_f32_16x16x32_bf16(a[i], b[j], acc[i][j], 0, 0, 0);
        __syncthreads();  // all reads done before next staging overwrite
    }

    // epilogue: out[tok][col] += g * (acc + bk[e][col]); exactly 2 adds/element
    const int colbase = nt * BN + wn * 64 + lr;
    float bkv[4];
    #pragma unroll
    for (int j = 0; j < 4; ++j) bkv[j] = bk[e * D_ + colbase + j * 16];

    #pragma unroll
    for (int i = 0; i < 4; ++i) {
        #pragma unroll
        for (int r = 0; r < 4; ++r) {
            const int row = wm * 64 + i * 16 + quad * 4 + r;  // C: row = quad*4+reg
            if (mt * BM + row < cnt) {
                const uint2 en = ent[row];
                const float g = __uint_as_float(en.y);
                float* orow = out + (size_t)en.x * D_ + colbase;
                #pragma unroll
                for (int j = 0; j < 4; ++j)
                    atomicAdd(orow + j * 16, g * (acc[i][j][r] + bkv[j]));
            }
        }
    }
}

// ---------------------------------------------------------------------------
// Launch
// ---------------------------------------------------------------------------
extern "C" void kernel_launch(void* const* d_in, const int* in_sizes, int n_in,
                              void* d_out, int out_size, void* d_ws, size_t ws_size,
                              hipStream_t stream) {
    const float* x   = (const float*)d_in[0];
    const float* eps = (const float*)d_in[1];
    const float* Wr  = (const float*)d_in[2];
    const float* br  = (const float*)d_in[3];
    const float* Wn  = (const float*)d_in[4];
    const float* bn  = (const float*)d_in[5];
    const float* Wk  = (const float*)d_in[6];
    const float* bk  = (const float*)d_in[7];
    float* out = (float*)d_out;

    // workspace layout (all 16B-aligned):
    //   [0,32)                      counts[E]
    //   [256, 256+1MiB)             entries[E][CAP] uint2
    //   [+, +16MiB)                 xb   bf16 [NTOK][D]
    //   [+, +4MiB)                  wkt  bf16 [E][D][D]
    char* ws = (char*)d_ws;
    int*            counts  = (int*)ws;
    uint2*          entries = (uint2*)(ws + 256);
    __hip_bfloat16* xb      = (__hip_bfloat16*)(ws + 256 + (size_t)E_ * CAP * 8);
    __hip_bfloat16* wkt     = (__hip_bfloat16*)(ws + 256 + (size_t)E_ * CAP * 8
                                                + (size_t)NTOK * D_ * 2);

    hipMemsetAsync(counts, 0, E_ * sizeof(int), stream);
    hipMemsetAsync(out, 0, (size_t)out_size * sizeof(float), stream);

    transpose_wk<<<dim3(D_ / 32, D_ / 32, E_), dim3(32, 8), 0, stream>>>(Wk, wkt);
    router_kernel<<<dim3(NTOK / 4), dim3(256), 0, stream>>>(
        x, eps, Wr, br, Wn, bn, xb, counts, entries);
    moe_gemm<<<dim3(D_ / 128, CAP / 128, E_), dim3(256), 0, stream>>>(
        xb, wkt, bk, counts, entries, out);
}

// Round 2
// 196.067 us; speedup vs baseline: 2.8948x; 2.8948x over previous
//
#include <hip/hip_runtime.h>
#include <hip/hip_bf16.h>
#include <math.h>

// Problem constants
#define B_    8
#define T_    2048
#define NTOK  (B_ * T_)   // 16384 tokens
#define D_    512
#define E_    8
#define CAP   NTOK        // per-expert bucket capacity (worst case)

typedef __attribute__((ext_vector_type(4))) float f32x4;
typedef __attribute__((ext_vector_type(8))) short short8;  // 8 bf16 = 4 VGPRs (MFMA a/b frag)

// ---------------------------------------------------------------------------
// async global->LDS, 16B per lane. LDS dest = wave-uniform base + lane*16.
// Global address may be per-lane scattered (gather is legal).
// ---------------------------------------------------------------------------
__device__ __forceinline__ void async_load16(const void* g, void* l) {
    __builtin_amdgcn_global_load_lds(
        (const __attribute__((address_space(1))) unsigned int*)g,
        (__attribute__((address_space(3))) unsigned int*)l,
        16, 0, 0);
}

// ---------------------------------------------------------------------------
// Kernel 0: router weight transpose Wr/Wn [D][E] -> [E][D] fp32, so the
// router's per-expert dot reads 2KB contiguous per wave (coalesced, L1-hot)
// instead of a 64-cache-line scatter per load instruction.
// ---------------------------------------------------------------------------
__global__ __launch_bounds__(256) void prep_router_w(
    const float* __restrict__ Wr, const float* __restrict__ Wn,
    float* __restrict__ WrT, float* __restrict__ WnT)
{
    const int idx = blockIdx.x * 256 + threadIdx.x;  // 4096 = D*E
    const int d = idx >> 3, e = idx & 7;
    WrT[e * D_ + d] = Wr[d * E_ + e];
    WnT[e * D_ + d] = Wn[d * E_ + e];
}

// ---------------------------------------------------------------------------
// Kernel 1: transpose + convert Wk[e][d][h] (fp32) -> Wkt[e][h][d] (bf16).
// B^T ([n][k]) row-major layout for contiguous ds_read_b128 B-fragments.
// ---------------------------------------------------------------------------
__global__ __launch_bounds__(256) void transpose_wk(
    const float* __restrict__ Wk, __hip_bfloat16* __restrict__ Wkt)
{
    __shared__ float tile[32][33];  // +1 pad: no bank conflicts
    const int e  = blockIdx.z;
    const int d0 = blockIdx.x * 32;  // d_in
    const int h0 = blockIdx.y * 32;  // d_out
    const int tx = threadIdx.x, ty = threadIdx.y;

    const float* src = Wk + ((size_t)e * D_ + d0) * D_ + h0;
    #pragma unroll
    for (int r = ty; r < 32; r += 8)
        tile[r][tx] = src[(size_t)r * D_ + tx];
    __syncthreads();
    __hip_bfloat16* dst = Wkt + ((size_t)e * D_ + h0) * D_ + d0;
    #pragma unroll
    for (int r = ty; r < 32; r += 8)
        dst[(size_t)r * D_ + tx] = __float2bfloat16(tile[tx][r]);
}

// ---------------------------------------------------------------------------
// Kernel 2: router compute. One wave per token, NO atomics (R1 showed the
// contended counts[] atomics serialized at ~407us). Writes per-token
// {i1|i2<<8, g1, g2} packed; bucket build happens in kernel 3.
// fp32 router throughout: bf16 could flip near-tied top-2 picks.
// ---------------------------------------------------------------------------
__global__ __launch_bounds__(256) void router_kernel(
    const float* __restrict__ x,     // [NTOK][D]
    const float* __restrict__ eps,   // [NTOK][E]
    const float* __restrict__ WrT,   // [E][D]
    const float* __restrict__ br,    // [E]
    const float* __restrict__ WnT,   // [E][D]
    const float* __restrict__ bn,    // [E]
    __hip_bfloat16* __restrict__ xb, // out: [NTOK][D] bf16
    uint4* __restrict__ top2)        // out: [NTOK] {i1|i2<<8, g1bits, g2bits, 0}
{
    const int lane = threadIdx.x & 63;
    const int tok  = blockIdx.x * 4 + (threadIdx.x >> 6);

    const float* xrow = x + (size_t)tok * D_;
    float xv[8];
    *(f32x4*)(xv)     = *(const f32x4*)(xrow + lane * 8);
    *(f32x4*)(xv + 4) = *(const f32x4*)(xrow + lane * 8 + 4);

    // fused bf16 conversion of x (coalesced 16B/lane store)
    union { __hip_bfloat16 h[8]; uint4 u; } cv;
    #pragma unroll
    for (int j = 0; j < 8; ++j) cv.h[j] = __float2bfloat16(xv[j]);
    *(uint4*)(xb + (size_t)tok * D_ + lane * 8) = cv.u;

    float aR[8], aN[8];
    #pragma unroll
    for (int e2 = 0; e2 < 8; ++e2) {
        union { f32x4 v[2]; float f[8]; } wr, wn;
        wr.v[0] = *(const f32x4*)(WrT + e2 * D_ + lane * 8);
        wr.v[1] = *(const f32x4*)(WrT + e2 * D_ + lane * 8 + 4);
        wn.v[0] = *(const f32x4*)(WnT + e2 * D_ + lane * 8);
        wn.v[1] = *(const f32x4*)(WnT + e2 * D_ + lane * 8 + 4);
        float r = 0.f, n = 0.f;
        #pragma unroll
        for (int j = 0; j < 8; ++j) {
            r = fmaf(xv[j], wr.f[j], r);
            n = fmaf(xv[j], wn.f[j], n);
        }
        aR[e2] = r; aN[e2] = n;
    }
    // butterfly reduce each of 16 accumulators across the 64-lane wave
    #pragma unroll
    for (int e2 = 0; e2 < 8; ++e2) {
        #pragma unroll
        for (int off = 32; off > 0; off >>= 1) {
            aR[e2] += __shfl_xor(aR[e2], off);
            aN[e2] += __shfl_xor(aN[e2], off);
        }
    }

    if (lane == 0) {
        float nv[8];
        #pragma unroll
        for (int e2 = 0; e2 < 8; ++e2) {
            const float nl = aN[e2] + bn[e2];
            // jax.nn.softplus = logaddexp(x, 0) = max(x,0) + log1p(exp(-|x|))
            const float sp = fmaxf(nl, 0.f) + log1pf(expf(-fabsf(nl)));
            nv[e2] = aR[e2] + br[e2] + eps[(size_t)tok * E_ + e2] * sp;
        }
        // top-2, lax.top_k tie semantics (lowest index wins ties)
        int i1 = 0; float v1 = nv[0];
        #pragma unroll
        for (int e2 = 1; e2 < 8; ++e2)
            if (nv[e2] > v1) { v1 = nv[e2]; i1 = e2; }
        int i2 = -1; float v2 = -3.4e38f;
        #pragma unroll
        for (int e2 = 0; e2 < 8; ++e2)
            if (e2 != i1 && nv[e2] > v2) { v2 = nv[e2]; i2 = e2; }
        const float t  = expf(v2 - v1);
        const float g1 = 1.f / (1.f + t);
        const float g2 = t / (1.f + t);
        top2[tok] = make_uint4((unsigned)i1 | ((unsigned)i2 << 8),
                               __float_as_uint(g1), __float_as_uint(g2), 0u);
    }
}

// ---------------------------------------------------------------------------
// Kernel 3: bucket build. Block = 256 tokens. LDS histogram -> ONE global
// atomic per expert per block (512 total vs 32768 contended in R1), then
// scatter entries. Entry: {tok | slot<<31, gate_bits}; slot selects the
// contribution plane in outg.
// ---------------------------------------------------------------------------
__global__ __launch_bounds__(256) void bucket_kernel(
    const uint4* __restrict__ top2,
    int* __restrict__ counts,     // [E] pre-zeroed
    uint2* __restrict__ entries)  // [E][CAP]
{
    __shared__ int hist[E_];
    __shared__ int base[E_];
    const int tid = threadIdx.x;
    const int tok = blockIdx.x * 256 + tid;
    if (tid < E_) hist[tid] = 0;
    __syncthreads();
    const uint4 t = top2[tok];
    const int i1 = t.x & 0xff, i2 = (t.x >> 8) & 0xff;
    const int l1 = atomicAdd(&hist[i1], 1);
    const int l2 = atomicAdd(&hist[i2], 1);
    __syncthreads();
    if (tid < E_) base[tid] = atomicAdd(counts + tid, hist[tid]);
    __syncthreads();
    entries[(size_t)i1 * CAP + base[i1] + l1] = make_uint2((unsigned)tok, t.y);
    entries[(size_t)i2 * CAP + base[i2] + l2] =
        make_uint2((unsigned)tok | 0x80000000u, t.z);
}

// ---------------------------------------------------------------------------
// Kernel 4: grouped expert GEMM. 128x128 tile, BK=32, 4 waves of 4x4
// mfma_f32_16x16x32_bf16, global_load_lds(16B) staging.
// Epilogue: if use_slots, PLAIN stores of g*(acc+bk) into outg[slot][tok]
// (no atomics; combine kernel sums the two planes). Else atomicAdd into out.
// ---------------------------------------------------------------------------
__global__ __launch_bounds__(256) void moe_gemm(
    const __hip_bfloat16* __restrict__ xb,   // [NTOK][D] bf16
    const __hip_bfloat16* __restrict__ wkt,  // [E][D(out)][D(in)] bf16 (B^T)
    const float* __restrict__ bk,            // [E][D]
    const int* __restrict__ counts,          // [E]
    const uint2* __restrict__ entries,       // [E][CAP]
    float* __restrict__ outg,                // [2][NTOK][D] fp32 (slot planes)
    float* __restrict__ out,                 // [NTOK][D] fp32 (atomic fallback)
    int use_slots)
{
    constexpr int BM = 128, BN = 128, BK = 32;
    __shared__ __hip_bfloat16 As[BM * BK];   // [m][k] packed
    __shared__ __hip_bfloat16 Bs[BN * BK];   // [n][k] packed
    __shared__ uint2 ent[BM];

    const int e  = blockIdx.z;
    const int mt = blockIdx.y;
    const int nt = blockIdx.x;
    const int cnt = counts[e];
    if (mt * BM >= cnt) return;  // uniform early-exit for unused tiles

    const int tid = threadIdx.x;
    const int wave = tid >> 6, lane = tid & 63;

    if (tid < BM) {
        const int idx = mt * BM + tid;
        ent[tid] = (idx < cnt) ? entries[(size_t)e * CAP + idx] : make_uint2(0u, 0u);
    }
    __syncthreads();

    const int quad = lane >> 4, lr = lane & 15;
    const int wm = wave >> 1, wn = wave & 1;
    const int sub = lane >> 2, part = lane & 3;  // staging: 16 rows x 4 chunks

    f32x4 acc[4][4];
    #pragma unroll
    for (int i = 0; i < 4; ++i)
        #pragma unroll
        for (int j = 0; j < 4; ++j) acc[i][j] = (f32x4){0.f, 0.f, 0.f, 0.f};

    const size_t tok0 = ent[wave * 32 + sub].x & 0x7fffffffu;
    const size_t tok1 = ent[wave * 32 + 16 + sub].x & 0x7fffffffu;
    const size_t brow0 = (size_t)e * D_ + nt * BN + wave * 32 + sub;

    for (int k0 = 0; k0 < D_; k0 += BK) {
        async_load16(xb + tok0 * D_ + k0 + part * 8, As + (wave * 32) * BK);
        async_load16(xb + tok1 * D_ + k0 + part * 8, As + (wave * 32 + 16) * BK);
        async_load16(wkt + brow0 * D_ + k0 + part * 8, Bs + (wave * 32) * BK);
        async_load16(wkt + (brow0 + 16) * D_ + k0 + part * 8, Bs + (wave * 32 + 16) * BK);
        __syncthreads();

        short8 a[4], b[4];
        #pragma unroll
        for (int i = 0; i < 4; ++i)
            a[i] = *(const short8*)(As + (wm * 64 + i * 16 + lr) * BK + quad * 8);
        #pragma unroll
        for (int j = 0; j < 4; ++j)
            b[j] = *(const short8*)(Bs + (wn * 64 + j * 16 + lr) * BK + quad * 8);
        #pragma unroll
        for (int i = 0; i < 4; ++i)
            #pragma unroll
            for (int j = 0; j < 4; ++j)
                acc[i][j] = __builtin_amdgcn_mfma_f32_16x16x32_bf16(a[i], b[j], acc[i][j], 0, 0, 0);
        __syncthreads();
    }

    const int colbase = nt * BN + wn * 64 + lr;
    float bkv[4];
    #pragma unroll
    for (int j = 0; j < 4; ++j) bkv[j] = bk[e * D_ + colbase + j * 16];

    #pragma unroll
    for (int i = 0; i < 4; ++i) {
        #pragma unroll
        for (int r = 0; r < 4; ++r) {
            const int row = wm * 64 + i * 16 + quad * 4 + r;  // C: row = quad*4+reg
            if (mt * BM + row < cnt) {
                const uint2 en = ent[row];
                const unsigned ts = en.x;
                const float g = __uint_as_float(en.y);
                if (use_slots) {
                    float* orow = outg + ((size_t)(ts >> 31) * NTOK
                                          + (ts & 0x7fffffffu)) * D_ + colbase;
                    #pragma unroll
                    for (int j = 0; j < 4; ++j)
                        orow[j * 16] = g * (acc[i][j][r] + bkv[j]);
                } else {
                    float* orow = out + (size_t)(ts & 0x7fffffffu) * D_ + colbase;
                    #pragma unroll
                    for (int j = 0; j < 4; ++j)
                        atomicAdd(orow + j * 16, g * (acc[i][j][r] + bkv[j]));
                }
            }
        }
    }
}

// ---------------------------------------------------------------------------
// Kernel 5: combine the two slot planes. Fully writes d_out.
// ---------------------------------------------------------------------------
__global__ __launch_bounds__(256) void combine_kernel(
    const float* __restrict__ outg, float* __restrict__ out)
{
    const size_t i = ((size_t)blockIdx.x * 256 + threadIdx.x) * 4;
    const f32x4 a = *(const f32x4*)(outg + i);
    const f32x4 b = *(const f32x4*)(outg + (size_t)NTOK * D_ + i);
    *(f32x4*)(out + i) = a + b;
}

// ---------------------------------------------------------------------------
// Launch
// ---------------------------------------------------------------------------
extern "C" void kernel_launch(void* const* d_in, const int* in_sizes, int n_in,
                              void* d_out, int out_size, void* d_ws, size_t ws_size,
                              hipStream_t stream) {
    const float* x   = (const float*)d_in[0];
    const float* eps = (const float*)d_in[1];
    const float* Wr  = (const float*)d_in[2];
    const float* br  = (const float*)d_in[3];
    const float* Wn  = (const float*)d_in[4];
    const float* bn  = (const float*)d_in[5];
    const float* Wk  = (const float*)d_in[6];
    const float* bk  = (const float*)d_in[7];
    float* out = (float*)d_out;

    // workspace layout (all 256B-aligned)
    char* ws = (char*)d_ws;
    size_t off = 0;
    int* counts = (int*)(ws + off);               off += 256;
    uint2* entries = (uint2*)(ws + off);          off += (size_t)E_ * CAP * 8;   // 1 MiB
    __hip_bfloat16* xb = (__hip_bfloat16*)(ws + off);  off += (size_t)NTOK * D_ * 2;  // 16 MiB
    __hip_bfloat16* wkt = (__hip_bfloat16*)(ws + off); off += (size_t)E_ * D_ * D_ * 2; // 4 MiB
    float* WrT = (float*)(ws + off);              off += (size_t)E_ * D_ * 4;    // 16 KiB
    float* WnT = (float*)(ws + off);              off += (size_t)E_ * D_ * 4;    // 16 KiB
    uint4* top2 = (uint4*)(ws + off);             off += (size_t)NTOK * 16;      // 256 KiB
    float* outg = (float*)(ws + off);             off += (size_t)2 * NTOK * D_ * 4; // 64 MiB
    const int use_slots = (ws_size >= off) ? 1 : 0;

    hipMemsetAsync(counts, 0, E_ * sizeof(int), stream);
    if (!use_slots)
        hipMemsetAsync(out, 0, (size_t)out_size * sizeof(float), stream);

    prep_router_w<<<dim3((D_ * E_) / 256), dim3(256), 0, stream>>>(Wr, Wn, WrT, WnT);
    transpose_wk<<<dim3(D_ / 32, D_ / 32, E_), dim3(32, 8), 0, stream>>>(Wk, wkt);
    router_kernel<<<dim3(NTOK / 4), dim3(256), 0, stream>>>(
        x, eps, WrT, br, WnT, bn, xb, top2);
    bucket_kernel<<<dim3(NTOK / 256), dim3(256), 0, stream>>>(top2, counts, entries);
    moe_gemm<<<dim3(D_ / 128, CAP / 128, E_), dim3(256), 0, stream>>>(
        xb, wkt, bk, counts, entries, outg, out, use_slots);
    if (use_slots)
        combine_kernel<<<dim3((NTOK * D_) / 1024), dim3(256), 0, stream>>>(outg, out);
}